// Round 1
// baseline (525.833 us; speedup 1.0000x reference)
//
#include <hip/hip_runtime.h>

// dims (hard-coded for this problem)
#define S_   2048
#define BB   2
#define MR   4096   // BB*S_
#define DM   2048
#define HH   32
#define DH   64
#define GG   8
#define NST  128
#define NC   8
#define LCH  256
#define KD   2048

typedef __attribute__((ext_vector_type(4))) float f32x4;
typedef __attribute__((ext_vector_type(8))) short bf16x8;

__device__ __forceinline__ short f2bf(float f) {
  unsigned u = __builtin_bit_cast(unsigned, f);
  u += 0x7FFFu + ((u >> 16) & 1u);
  return (short)(u >> 16);
}
__device__ __forceinline__ float bf2f(short s) {
  unsigned u = ((unsigned)(unsigned short)s) << 16;
  return __builtin_bit_cast(float, u);
}
__device__ __forceinline__ unsigned pack2(short lo, short hi) {
  return (unsigned)(unsigned short)lo | ((unsigned)(unsigned short)hi << 16);
}

// ---------------- casts ----------------
__global__ void k_cast(const float* __restrict__ src, short* __restrict__ dst, int n8) {
  int i = blockIdx.x * 256 + threadIdx.x;
  if (i >= n8) return;
  const float4 a = *(const float4*)(src + (size_t)i * 8);
  const float4 b = *(const float4*)(src + (size_t)i * 8 + 4);
  uint4 o;
  o.x = pack2(f2bf(a.x), f2bf(a.y));
  o.y = pack2(f2bf(a.z), f2bf(a.w));
  o.z = pack2(f2bf(b.x), f2bf(b.y));
  o.w = pack2(f2bf(b.z), f2bf(b.w));
  *(uint4*)(dst + (size_t)i * 8) = o;
}

// transpose fp32 [K][N] -> bf16 [N][K]
__global__ __launch_bounds__(256) void k_cast_T(const float* __restrict__ src,
                                                short* __restrict__ dst, int K, int N) {
  __shared__ short t[32][33];
  int bx = blockIdx.x * 32, by = blockIdx.y * 32;
  int tx = threadIdx.x & 31, ty = threadIdx.x >> 5;
  for (int r = ty; r < 32; r += 8)
    t[r][tx] = f2bf(src[(size_t)(by + r) * N + bx + tx]);
  __syncthreads();
  for (int r = ty; r < 32; r += 8)
    dst[(size_t)(bx + r) * K + by + tx] = t[tx][r];
}

// ---------------- GEMM: A[M][K] bf16  x  Bt[N][K] bf16  -> out (+bias) ----------------
template <int OUT_BF16>
__global__ __launch_bounds__(256) void k_gemm(const short* __restrict__ A,
                                              const short* __restrict__ Bt,
                                              const float* __restrict__ bias,
                                              void* __restrict__ out, int M, int N, int K) {
  __shared__ short As[64 * 40];
  __shared__ short Bs[64 * 40];
  const int tid = threadIdx.x;
  const int bm = blockIdx.y * 64, bn = blockIdx.x * 64;
  const int wid = tid >> 6, lane = tid & 63, lg = lane >> 4, lr = lane & 15;
  const int wr = wid >> 1, wc = wid & 1;
  const int arow = tid >> 2, aseg = (tid & 3) * 8;
  const bool bok = (bn + arow) < N;
  const short* Arow = A + (size_t)(bm + arow) * K + aseg;
  const short* Brow = Bt + (size_t)(bn + arow) * K + aseg;
  f32x4 acc[2][2] = {};
  for (int k0 = 0; k0 < K; k0 += 32) {
    uint4 av = *(const uint4*)(Arow + k0);
    uint4 bv;
    if (bok) bv = *(const uint4*)(Brow + k0);
    else     bv = make_uint4(0u, 0u, 0u, 0u);
    __syncthreads();
    *(uint4*)(As + arow * 40 + aseg) = av;
    *(uint4*)(Bs + arow * 40 + aseg) = bv;
    __syncthreads();
    bf16x8 af0 = *(const bf16x8*)(As + (wr * 32 + lr) * 40 + lg * 8);
    bf16x8 af1 = *(const bf16x8*)(As + (wr * 32 + 16 + lr) * 40 + lg * 8);
    bf16x8 bf0 = *(const bf16x8*)(Bs + (wc * 32 + lr) * 40 + lg * 8);
    bf16x8 bf1 = *(const bf16x8*)(Bs + (wc * 32 + 16 + lr) * 40 + lg * 8);
    acc[0][0] = __builtin_amdgcn_mfma_f32_16x16x32_bf16(af0, bf0, acc[0][0], 0, 0, 0);
    acc[0][1] = __builtin_amdgcn_mfma_f32_16x16x32_bf16(af0, bf1, acc[0][1], 0, 0, 0);
    acc[1][0] = __builtin_amdgcn_mfma_f32_16x16x32_bf16(af1, bf0, acc[1][0], 0, 0, 0);
    acc[1][1] = __builtin_amdgcn_mfma_f32_16x16x32_bf16(af1, bf1, acc[1][1], 0, 0, 0);
  }
  for (int mi = 0; mi < 2; ++mi)
    for (int ni = 0; ni < 2; ++ni) {
      int col = bn + wc * 32 + ni * 16 + lr;
      if (col >= N) continue;
      float bv = bias[col];
      int row0 = bm + wr * 32 + mi * 16 + lg * 4;
      for (int r = 0; r < 4; ++r) {
        float v = acc[mi][ni][r] + bv;
        if (OUT_BF16) ((short*)out)[(size_t)(row0 + r) * N + col] = f2bf(v);
        else          ((float*)out)[(size_t)(row0 + r) * N + col] = v;
      }
    }
}

// ---------------- small elementwise ----------------
__global__ void k_dt(const float* __restrict__ dtraw, const float* __restrict__ A_log,
                     float* __restrict__ dtsp, float* __restrict__ adt, int n) {
  int i = blockIdx.x * 256 + threadIdx.x;
  if (i >= n) return;
  int h = i & (HH - 1);
  float z = dtraw[i];
  float sp = (z > 20.f) ? z : log1pf(expf(z));
  dtsp[i] = sp;
  adt[i] = -expf(A_log[h]) * sp;
}

__global__ void k_xdt(const float* __restrict__ xraw, const float* __restrict__ dtsp,
                      short* __restrict__ xbf, int n4) {
  int i = blockIdx.x * 256 + threadIdx.x;
  if (i >= n4) return;
  size_t e = (size_t)i * 4;
  int row = (int)(e >> 11);
  int col = (int)(e & (DM - 1));
  int h = col >> 6;
  float dt = dtsp[row * HH + h];
  float4 v = *(const float4*)(xraw + e);
  uint2 o;
  o.x = pack2(f2bf(v.x * dt), f2bf(v.y * dt));
  o.y = pack2(f2bf(v.z * dt), f2bf(v.w * dt));
  *(uint2*)(xbf + e) = o;
}

// per-(b,h,chunk) inclusive cumsum of Adt
__global__ __launch_bounds__(256) void k_scan(const float* __restrict__ adt,
                                              float* __restrict__ acs,
                                              float* __restrict__ asum) {
  int blk = blockIdx.x;
  int h = blk & 31, ci = (blk >> 5) & 7, b = blk >> 8;
  int l = threadIdx.x;
  __shared__ float sc[256];
  sc[l] = adt[(size_t)(b * S_ + ci * LCH + l) * HH + h];
  __syncthreads();
  for (int o = 1; o < 256; o <<= 1) {
    float t = (l >= o) ? sc[l - o] : 0.f;
    float own = sc[l];
    __syncthreads();
    sc[l] = own + t;
    __syncthreads();
  }
  float r = sc[l];
  acs[((size_t)((b * HH + h) * NC + ci)) * LCH + l] = r;
  if (l == 255) asum[(b * HH + h) * NC + ci] = r;
}

__global__ void k_colsum(const float* __restrict__ asum, float* __restrict__ csum) {
  int t = threadIdx.x;
  if (t >= BB * HH) return;
  float av[NC];
  for (int k = 0; k < NC; ++k) av[k] = asum[t * NC + k];
  for (int z = 0; z < NC; ++z) {
    float run = 0.f, acc = 1.f;
    for (int j = z; j < NC; ++j) { run += av[j]; acc += __expf(run); }
    csum[t * NC + z] = acc;
  }
}

// ---------------- states: state[d][n] = sum_l B[l][n]*exp(Asum-A_cs[l]) * x[l][d] ----------------
__global__ __launch_bounds__(256) void k_states(const short* __restrict__ Bbf,
                                                const short* __restrict__ xdt,
                                                const float* __restrict__ acs,
                                                const float* __restrict__ asum,
                                                short* __restrict__ state) {
  int blk = blockIdx.x;
  int h = blk & 31, ci = (blk >> 5) & 7, b = blk >> 8;
  int g = h & 7;
  int tid = threadIdx.x, wid = tid >> 6, lane = tid & 63, lg = lane >> 4, lr = lane & 15;
  __shared__ float dsh[256];
  __shared__ short Bt[128 * 40];  // [n][l_local]
  __shared__ short Xt[64 * 40];   // [d][l_local]
  const float* acs_p = acs + ((size_t)((b * HH + h) * NC + ci)) * LCH;
  float last = asum[(b * HH + h) * NC + ci];
  dsh[tid] = __expf(last - acs_p[tid]);
  const short* Bbase = Bbf + ((size_t)(b * S_ + ci * LCH) * GG + g) * NST;
  const short* Xbase = xdt + (size_t)(b * S_ + ci * LCH) * DM + h * DH;
  const int lrow = tid >> 3, nseg = (tid & 7) * 16, dseg = (tid & 7) * 8;
  f32x4 acc[2][4] = {};
  for (int l0 = 0; l0 < LCH; l0 += 32) {
    uint4 b0 = *(const uint4*)(Bbase + (size_t)(l0 + lrow) * (GG * NST) + nseg);
    uint4 b1 = *(const uint4*)(Bbase + (size_t)(l0 + lrow) * (GG * NST) + nseg + 8);
    uint4 xv = *(const uint4*)(Xbase + (size_t)(l0 + lrow) * DM + dseg);
    __syncthreads();
    float dly = dsh[l0 + lrow];
    const short* bp0 = (const short*)&b0;
    for (int e = 0; e < 8; ++e) Bt[(nseg + e) * 40 + lrow] = f2bf(bf2f(bp0[e]) * dly);
    const short* bp1 = (const short*)&b1;
    for (int e = 0; e < 8; ++e) Bt[(nseg + 8 + e) * 40 + lrow] = f2bf(bf2f(bp1[e]) * dly);
    const short* xp = (const short*)&xv;
    for (int e = 0; e < 8; ++e) Xt[(dseg + e) * 40 + lrow] = xp[e];
    __syncthreads();
    bf16x8 afr[2], bfr[4];
    for (int mi = 0; mi < 2; ++mi)
      afr[mi] = *(const bf16x8*)(Bt + (wid * 32 + mi * 16 + lr) * 40 + lg * 8);
    for (int ni = 0; ni < 4; ++ni)
      bfr[ni] = *(const bf16x8*)(Xt + (ni * 16 + lr) * 40 + lg * 8);
    for (int mi = 0; mi < 2; ++mi)
      for (int ni = 0; ni < 4; ++ni)
        acc[mi][ni] = __builtin_amdgcn_mfma_f32_16x16x32_bf16(afr[mi], bfr[ni], acc[mi][ni], 0, 0, 0);
  }
  short* sp = state + (size_t)blk * DH * NST;
  for (int mi = 0; mi < 2; ++mi)
    for (int ni = 0; ni < 4; ++ni)
      for (int r = 0; r < 4; ++r) {
        int n = wid * 32 + mi * 16 + lg * 4 + r;
        int d = ni * 16 + lr;
        sp[d * NST + n] = f2bf(acc[mi][ni][r]);
      }
}

// ---------------- Y kernel: Y_off + triangular Y_diag + D*x, writes bf16 ----------------
__global__ __launch_bounds__(256) void k_y(const short* __restrict__ Cbf,
                                           const short* __restrict__ Bbf,
                                           const short* __restrict__ xdt,
                                           const float* __restrict__ xraw,
                                           const float* __restrict__ acs,
                                           const float* __restrict__ csum,
                                           const short* __restrict__ state,
                                           const float* __restrict__ Dv,
                                           short* __restrict__ Ybuf) {
  int blk = blockIdx.x;
  int h = blk & 31, ci = (blk >> 5) & 7, b = blk >> 8;
  int g = h & 7;
  int tid = threadIdx.x, wid = tid >> 6, lane = tid & 63, lg = lane >> 4, lr = lane & 15;
  __shared__ float ash[256];
  __shared__ short Xt[64 * 264];    // [d][l], stride 264
  __shared__ short Mld[4][64 * 40]; // per-wave M tile
  const float* acs_p = acs + ((size_t)((b * HH + h) * NC + ci)) * LCH;
  ash[tid] = acs_p[tid];
  float cs = csum[(b * HH + h) * NC + ci];
  const short* Xbase = xdt + (size_t)(b * S_ + ci * LCH) * DM + h * DH;
  {
    const short* xr = Xbase + (size_t)tid * DM;
    for (int d0 = 0; d0 < DH; d0 += 8) {
      uint4 v = *(const uint4*)(xr + d0);
      const short* vp = (const short*)&v;
      for (int e = 0; e < 8; ++e) Xt[(d0 + e) * 264 + tid] = vp[e];
    }
  }
  __syncthreads();
  f32x4 acc[4][4] = {};
  const short* Crow0 = Cbf + ((size_t)(b * S_ + ci * LCH) * GG + g) * NST;
  // ---- Y_off: C @ state_{ci-1}^T, scaled by exp(A_cs[i]) * col_sum ----
  if (ci > 0) {
    const short* sp = state + (size_t)((b * NC + ci - 1) * HH + h) * DH * NST;
    for (int n0 = 0; n0 < NST; n0 += 32) {
      bf16x8 afr[4], bfr[4];
      for (int mi = 0; mi < 4; ++mi)
        afr[mi] = *(const bf16x8*)(Crow0 + (size_t)(wid * 64 + mi * 16 + lr) * (GG * NST) + n0 + lg * 8);
      for (int ni = 0; ni < 4; ++ni)
        bfr[ni] = *(const bf16x8*)(sp + (ni * 16 + lr) * NST + n0 + lg * 8);
      for (int mi = 0; mi < 4; ++mi)
        for (int ni = 0; ni < 4; ++ni)
          acc[mi][ni] = __builtin_amdgcn_mfma_f32_16x16x32_bf16(afr[mi], bfr[ni], acc[mi][ni], 0, 0, 0);
    }
    for (int mi = 0; mi < 4; ++mi)
      for (int r = 0; r < 4; ++r) {
        int i = wid * 64 + mi * 16 + lg * 4 + r;
        float f = __expf(ash[i]) * cs;
        for (int ni = 0; ni < 4; ++ni) acc[mi][ni][r] *= f;
      }
  }
  // ---- Y_diag: per-wave triangular j-tile loop (no cross-wave sync) ----
  short* Ml = &Mld[wid][0];
  int jtmax = (wid * 64 + 63) >> 5;
  for (int jt = 0; jt <= jtmax; ++jt) {
    f32x4 gacc[4][2] = {};
    for (int n0 = 0; n0 < NST; n0 += 32) {
      bf16x8 afr[4], bfr[2];
      for (int mi = 0; mi < 4; ++mi)
        afr[mi] = *(const bf16x8*)(Crow0 + (size_t)(wid * 64 + mi * 16 + lr) * (GG * NST) + n0 + lg * 8);
      for (int nj = 0; nj < 2; ++nj) {
        int j = jt * 32 + nj * 16 + lr;
        bfr[nj] = *(const bf16x8*)(Bbf + ((size_t)(b * S_ + ci * LCH + j) * GG + g) * NST + n0 + lg * 8);
      }
      for (int mi = 0; mi < 4; ++mi)
        for (int nj = 0; nj < 2; ++nj)
          gacc[mi][nj] = __builtin_amdgcn_mfma_f32_16x16x32_bf16(afr[mi], bfr[nj], gacc[mi][nj], 0, 0, 0);
    }
    for (int mi = 0; mi < 4; ++mi)
      for (int nj = 0; nj < 2; ++nj)
        for (int r = 0; r < 4; ++r) {
          int i = wid * 64 + mi * 16 + lg * 4 + r;
          int jc = jt * 32 + nj * 16 + lr;
          float v = 0.f;
          if (jc <= i) v = gacc[mi][nj][r] * __expf(ash[i] - ash[jc]);
          Ml[(mi * 16 + lg * 4 + r) * 40 + nj * 16 + lr] = f2bf(v);
        }
    bf16x8 mfr[4], xfr[4];
    for (int mi = 0; mi < 4; ++mi) mfr[mi] = *(const bf16x8*)(Ml + (mi * 16 + lr) * 40 + lg * 8);
    for (int ni = 0; ni < 4; ++ni) xfr[ni] = *(const bf16x8*)(Xt + (ni * 16 + lr) * 264 + jt * 32 + lg * 8);
    for (int mi = 0; mi < 4; ++mi)
      for (int ni = 0; ni < 4; ++ni)
        acc[mi][ni] = __builtin_amdgcn_mfma_f32_16x16x32_bf16(mfr[mi], xfr[ni], acc[mi][ni], 0, 0, 0);
  }
  // ---- epilogue: + D[h]*x_raw, write bf16 ----
  float Dh = Dv[h];
  const float* xr0 = xraw + (size_t)(b * S_ + ci * LCH) * DM + h * DH;
  short* yb = Ybuf + (size_t)(b * S_ + ci * LCH) * DM + h * DH;
  for (int mi = 0; mi < 4; ++mi)
    for (int r = 0; r < 4; ++r) {
      int i = wid * 64 + mi * 16 + lg * 4 + r;
      for (int ni = 0; ni < 4; ++ni) {
        int d = ni * 16 + lr;
        float v = acc[mi][ni][r] + Dh * xr0[(size_t)i * DM + d];
        yb[(size_t)i * DM + d] = f2bf(v);
      }
    }
}

extern "C" void kernel_launch(void* const* d_in, const int* in_sizes, int n_in,
                              void* d_out, int out_size, void* d_ws, size_t ws_size,
                              hipStream_t stream) {
  const float* hs    = (const float*)d_in[0];
  const float* A_log = (const float*)d_in[1];
  const float* Dv    = (const float*)d_in[2];
  const float* W_B   = (const float*)d_in[3];
  const float* b_B   = (const float*)d_in[4];
  const float* W_C   = (const float*)d_in[5];
  const float* b_C   = (const float*)d_in[6];
  const float* W_x   = (const float*)d_in[7];
  const float* b_x   = (const float*)d_in[8];
  const float* W_dt  = (const float*)d_in[9];
  const float* b_dt  = (const float*)d_in[10];
  const float* W_out = (const float*)d_in[11];
  const float* b_out = (const float*)d_in[12];

  char* w = (char*)d_ws;
  size_t off = 0;
  auto alloc = [&](size_t bytes) -> char* {
    char* p = w + off;
    off += (bytes + 255) & ~(size_t)255;
    return p;
  };
  short* hs_bf = (short*)alloc((size_t)MR * DM * 2);
  short* WxT   = (short*)alloc((size_t)DM * DM * 2);
  short* WBT   = (short*)alloc((size_t)1024 * DM * 2);
  short* WCT   = (short*)alloc((size_t)1024 * DM * 2);
  short* WdtT  = (short*)alloc((size_t)32 * DM * 2);
  short* WoutT = (short*)alloc((size_t)DM * DM * 2);
  float* xraw  = (float*)alloc((size_t)MR * DM * 4);
  short* Bbf   = (short*)alloc((size_t)MR * 1024 * 2);
  short* Cbf   = (short*)alloc((size_t)MR * 1024 * 2);
  float* dtraw = (float*)alloc((size_t)MR * HH * 4);
  float* dtsp  = (float*)alloc((size_t)MR * HH * 4);
  float* adt   = (float*)alloc((size_t)MR * HH * 4);
  float* acs   = (float*)alloc((size_t)BB * HH * NC * LCH * 4);
  float* asum  = (float*)alloc((size_t)BB * HH * NC * 4);
  float* csum  = (float*)alloc((size_t)BB * HH * NC * 4);
  short* state = (short*)alloc((size_t)BB * NC * HH * DH * NST * 2);
  short* xdtbf = (short*)alloc((size_t)MR * DM * 2);
  short* Ybuf  = (short*)alloc((size_t)MR * DM * 2);
  (void)ws_size; (void)in_sizes; (void)n_in; (void)out_size;

  // casts / transposes
  k_cast<<<(MR * DM / 8 + 255) / 256, 256, 0, stream>>>(hs, hs_bf, MR * DM / 8);
  k_cast_T<<<dim3(DM / 32, DM / 32), 256, 0, stream>>>(W_x, WxT, DM, DM);
  k_cast_T<<<dim3(1024 / 32, DM / 32), 256, 0, stream>>>(W_B, WBT, DM, 1024);
  k_cast_T<<<dim3(1024 / 32, DM / 32), 256, 0, stream>>>(W_C, WCT, DM, 1024);
  k_cast_T<<<dim3(1, DM / 32), 256, 0, stream>>>(W_dt, WdtT, DM, 32);
  k_cast_T<<<dim3(DM / 32, DM / 32), 256, 0, stream>>>(W_out, WoutT, DM, DM);

  // projections
  k_gemm<0><<<dim3(1, MR / 64), 256, 0, stream>>>(hs_bf, WdtT, b_dt, dtraw, MR, 32, KD);
  k_gemm<0><<<dim3(DM / 64, MR / 64), 256, 0, stream>>>(hs_bf, WxT, b_x, xraw, MR, DM, KD);
  k_gemm<1><<<dim3(1024 / 64, MR / 64), 256, 0, stream>>>(hs_bf, WBT, b_B, Bbf, MR, 1024, KD);
  k_gemm<1><<<dim3(1024 / 64, MR / 64), 256, 0, stream>>>(hs_bf, WCT, b_C, Cbf, MR, 1024, KD);

  // elementwise + scans
  k_dt<<<(MR * HH + 255) / 256, 256, 0, stream>>>(dtraw, A_log, dtsp, adt, MR * HH);
  k_xdt<<<(MR * DM / 4 + 255) / 256, 256, 0, stream>>>(xraw, dtsp, xdtbf, MR * DM / 4);
  k_scan<<<BB * HH * NC, 256, 0, stream>>>(adt, acs, asum);
  k_colsum<<<1, 64, 0, stream>>>(asum, csum);

  // SSD core
  k_states<<<BB * NC * HH, 256, 0, stream>>>(Bbf, xdtbf, acs, asum, state);
  k_y<<<BB * NC * HH, 256, 0, stream>>>(Cbf, Bbf, xdtbf, xraw, acs, csum, state, Dv, Ybuf);

  // output projection
  k_gemm<0><<<dim3(DM / 64, MR / 64), 256, 0, stream>>>(Ybuf, WoutT, b_out, (float*)d_out, MR, DM, KD);
}

// Round 4
// 470.784 us; speedup vs baseline: 1.1169x; 1.1169x over previous
//
#include <hip/hip_runtime.h>

// dims (hard-coded for this problem)
#define S_   2048
#define BB   2
#define MR   4096   // BB*S_
#define DM   2048
#define HH   32
#define DH   64
#define GG   8
#define NST  128
#define NC   8
#define LCH  256
#define KD   2048

typedef __attribute__((ext_vector_type(4))) float f32x4;
typedef __attribute__((ext_vector_type(8))) short bf16x8;

typedef __attribute__((address_space(1))) const void gvoid;
typedef __attribute__((address_space(3))) void lvoid;

__device__ __forceinline__ short f2bf(float f) {
  unsigned u = __builtin_bit_cast(unsigned, f);
  u += 0x7FFFu + ((u >> 16) & 1u);
  return (short)(u >> 16);
}
__device__ __forceinline__ float bf2f(short s) {
  unsigned u = ((unsigned)(unsigned short)s) << 16;
  return __builtin_bit_cast(float, u);
}
__device__ __forceinline__ unsigned pack2(short lo, short hi) {
  return (unsigned)(unsigned short)lo | ((unsigned)(unsigned short)hi << 16);
}

// ---------------- casts ----------------
__global__ void k_cast(const float* __restrict__ src, short* __restrict__ dst, int n8) {
  int i = blockIdx.x * 256 + threadIdx.x;
  if (i >= n8) return;
  const float4 a = *(const float4*)(src + (size_t)i * 8);
  const float4 b = *(const float4*)(src + (size_t)i * 8 + 4);
  uint4 o;
  o.x = pack2(f2bf(a.x), f2bf(a.y));
  o.y = pack2(f2bf(a.z), f2bf(a.w));
  o.z = pack2(f2bf(b.x), f2bf(b.y));
  o.w = pack2(f2bf(b.z), f2bf(b.w));
  *(uint4*)(dst + (size_t)i * 8) = o;
}

// transpose fp32 [K][N] -> bf16 [N][K]
__global__ __launch_bounds__(256) void k_cast_T(const float* __restrict__ src,
                                                short* __restrict__ dst, int K, int N) {
  __shared__ short t[32][33];
  int bx = blockIdx.x * 32, by = blockIdx.y * 32;
  int tx = threadIdx.x & 31, ty = threadIdx.x >> 5;
  for (int r = ty; r < 32; r += 8)
    t[r][tx] = f2bf(src[(size_t)(by + r) * N + bx + tx]);
  __syncthreads();
  for (int r = ty; r < 32; r += 8)
    dst[(size_t)(bx + r) * K + by + tx] = t[tx][r];
}

// ---------------- 64-tile GEMM (only for the tiny dt projection, N=32) ----------------
template <int OUT_BF16>
__global__ __launch_bounds__(256) void k_gemm(const short* __restrict__ A,
                                              const short* __restrict__ Bt,
                                              const float* __restrict__ bias,
                                              void* __restrict__ out, int M, int N, int K) {
  __shared__ short As[64 * 40];
  __shared__ short Bs[64 * 40];
  const int tid = threadIdx.x;
  const int bm = blockIdx.y * 64, bn = blockIdx.x * 64;
  const int wid = tid >> 6, lane = tid & 63, lg = lane >> 4, lr = lane & 15;
  const int wr = wid >> 1, wc = wid & 1;
  const int arow = tid >> 2, aseg = (tid & 3) * 8;
  const bool bok = (bn + arow) < N;
  const short* Arow = A + (size_t)(bm + arow) * K + aseg;
  const short* Brow = Bt + (size_t)(bn + arow) * K + aseg;
  f32x4 acc[2][2] = {};
  for (int k0 = 0; k0 < K; k0 += 32) {
    uint4 av = *(const uint4*)(Arow + k0);
    uint4 bv;
    if (bok) bv = *(const uint4*)(Brow + k0);
    else     bv = make_uint4(0u, 0u, 0u, 0u);
    __syncthreads();
    *(uint4*)(As + arow * 40 + aseg) = av;
    *(uint4*)(Bs + arow * 40 + aseg) = bv;
    __syncthreads();
    bf16x8 af0 = *(const bf16x8*)(As + (wr * 32 + lr) * 40 + lg * 8);
    bf16x8 af1 = *(const bf16x8*)(As + (wr * 32 + 16 + lr) * 40 + lg * 8);
    bf16x8 bf0 = *(const bf16x8*)(Bs + (wc * 32 + lr) * 40 + lg * 8);
    bf16x8 bf1 = *(const bf16x8*)(Bs + (wc * 32 + 16 + lr) * 40 + lg * 8);
    acc[0][0] = __builtin_amdgcn_mfma_f32_16x16x32_bf16(af0, bf0, acc[0][0], 0, 0, 0);
    acc[0][1] = __builtin_amdgcn_mfma_f32_16x16x32_bf16(af0, bf1, acc[0][1], 0, 0, 0);
    acc[1][0] = __builtin_amdgcn_mfma_f32_16x16x32_bf16(af1, bf0, acc[1][0], 0, 0, 0);
    acc[1][1] = __builtin_amdgcn_mfma_f32_16x16x32_bf16(af1, bf1, acc[1][1], 0, 0, 0);
  }
  for (int mi = 0; mi < 2; ++mi)
    for (int ni = 0; ni < 2; ++ni) {
      int col = bn + wc * 32 + ni * 16 + lr;
      if (col >= N) continue;
      float bv = bias[col];
      int row0 = bm + wr * 32 + mi * 16 + lg * 4;
      for (int r = 0; r < 4; ++r) {
        float v = acc[mi][ni][r] + bv;
        if (OUT_BF16) ((short*)out)[(size_t)(row0 + r) * N + col] = f2bf(v);
        else          ((float*)out)[(size_t)(row0 + r) * N + col] = v;
      }
    }
}

// ---------------- 128-tile GEMM, m97 structure (global_load_lds width=16) ----------------
// A[M][K] bf16 row-major, Bt[N][K] bf16 row-major; M,N,K multiples of 128/128/32.
template <int OUT_BF16>
__global__ __launch_bounds__(256) void k_gemm128(const short* __restrict__ A,
                                                 const short* __restrict__ Bt,
                                                 const float* __restrict__ bias,
                                                 void* __restrict__ out,
                                                 int M, int N, int K) {
  __shared__ short As[128 * 32];
  __shared__ short Bs[128 * 32];
  const int tid = threadIdx.x;
  const int bm = blockIdx.y * 128, bn = blockIdx.x * 128;
  const int wid = tid >> 6, lane = tid & 63, lg = lane >> 4, lr = lane & 15;
  const int wr = wid >> 1, wc = wid & 1;
  // staging geometry: thread tid covers row (tid>>2), k-seg (tid&3)*8 (16B)
  const int srow = tid >> 2, skseg = (tid & 3) * 8;
  const short* gA0 = A + (size_t)(bm + srow) * K + skseg;
  const short* gA1 = A + (size_t)(bm + 64 + srow) * K + skseg;
  const short* gB0 = Bt + (size_t)(bn + srow) * K + skseg;
  const short* gB1 = Bt + (size_t)(bn + 64 + srow) * K + skseg;
  char* lA = (char*)As + wid * 1024;   // wave-uniform LDS bases
  char* lB = (char*)Bs + wid * 1024;
  f32x4 acc[4][4] = {};
  for (int k0 = 0; k0 < K; k0 += 32) {
    __syncthreads();  // previous iteration's ds_reads complete
    __builtin_amdgcn_global_load_lds((gvoid*)(gA0 + k0), (lvoid*)lA, 16, 0, 0);
    __builtin_amdgcn_global_load_lds((gvoid*)(gA1 + k0), (lvoid*)(lA + 4096), 16, 0, 0);
    __builtin_amdgcn_global_load_lds((gvoid*)(gB0 + k0), (lvoid*)lB, 16, 0, 0);
    __builtin_amdgcn_global_load_lds((gvoid*)(gB1 + k0), (lvoid*)(lB + 4096), 16, 0, 0);
    __syncthreads();  // vmcnt(0) drain + barrier
    bf16x8 af[4], bfv[4];
    for (int mi = 0; mi < 4; ++mi)
      af[mi] = *(const bf16x8*)(As + (wr * 64 + mi * 16 + lr) * 32 + lg * 8);
    for (int ni = 0; ni < 4; ++ni)
      bfv[ni] = *(const bf16x8*)(Bs + (wc * 64 + ni * 16 + lr) * 32 + lg * 8);
    for (int mi = 0; mi < 4; ++mi)
      for (int ni = 0; ni < 4; ++ni)
        acc[mi][ni] = __builtin_amdgcn_mfma_f32_16x16x32_bf16(af[mi], bfv[ni], acc[mi][ni], 0, 0, 0);
  }
  for (int mi = 0; mi < 4; ++mi)
    for (int ni = 0; ni < 4; ++ni) {
      int col = bn + wc * 64 + ni * 16 + lr;
      float bv = bias[col];
      int row0 = bm + wr * 64 + mi * 16 + lg * 4;
      for (int r = 0; r < 4; ++r) {
        float v = acc[mi][ni][r] + bv;
        if (OUT_BF16) ((short*)out)[(size_t)(row0 + r) * N + col] = f2bf(v);
        else          ((float*)out)[(size_t)(row0 + r) * N + col] = v;
      }
    }
}

// ---------------- small elementwise ----------------
__global__ void k_dt(const float* __restrict__ dtraw, const float* __restrict__ A_log,
                     float* __restrict__ dtsp, float* __restrict__ adt, int n) {
  int i = blockIdx.x * 256 + threadIdx.x;
  if (i >= n) return;
  int h = i & (HH - 1);
  float z = dtraw[i];
  float sp = (z > 20.f) ? z : log1pf(expf(z));
  dtsp[i] = sp;
  adt[i] = -expf(A_log[h]) * sp;
}

__global__ void k_xdt(const float* __restrict__ xraw, const float* __restrict__ dtsp,
                      short* __restrict__ xbf, int n4) {
  int i = blockIdx.x * 256 + threadIdx.x;
  if (i >= n4) return;
  size_t e = (size_t)i * 4;
  int row = (int)(e >> 11);
  int col = (int)(e & (DM - 1));
  int h = col >> 6;
  float dt = dtsp[row * HH + h];
  float4 v = *(const float4*)(xraw + e);
  uint2 o;
  o.x = pack2(f2bf(v.x * dt), f2bf(v.y * dt));
  o.y = pack2(f2bf(v.z * dt), f2bf(v.w * dt));
  *(uint2*)(xbf + e) = o;
}

// per-(b,h,chunk) inclusive cumsum of Adt
__global__ __launch_bounds__(256) void k_scan(const float* __restrict__ adt,
                                              float* __restrict__ acs,
                                              float* __restrict__ asum) {
  int blk = blockIdx.x;
  int h = blk & 31, ci = (blk >> 5) & 7, b = blk >> 8;
  int l = threadIdx.x;
  __shared__ float sc[256];
  sc[l] = adt[(size_t)(b * S_ + ci * LCH + l) * HH + h];
  __syncthreads();
  for (int o = 1; o < 256; o <<= 1) {
    float t = (l >= o) ? sc[l - o] : 0.f;
    float own = sc[l];
    __syncthreads();
    sc[l] = own + t;
    __syncthreads();
  }
  float r = sc[l];
  acs[((size_t)((b * HH + h) * NC + ci)) * LCH + l] = r;
  if (l == 255) asum[(b * HH + h) * NC + ci] = r;
}

__global__ void k_colsum(const float* __restrict__ asum, float* __restrict__ csum) {
  int t = threadIdx.x;
  if (t >= BB * HH) return;
  float av[NC];
  for (int k = 0; k < NC; ++k) av[k] = asum[t * NC + k];
  for (int z = 0; z < NC; ++z) {
    float run = 0.f, acc = 1.f;
    for (int j = z; j < NC; ++j) { run += av[j]; acc += __expf(run); }
    csum[t * NC + z] = acc;
  }
}

// ---------------- states: state[d][n] = sum_l B[l][n]*exp(Asum-A_cs[l]) * x[l][d] ----------------
__global__ __launch_bounds__(256) void k_states(const short* __restrict__ Bbf,
                                                const short* __restrict__ xdt,
                                                const float* __restrict__ acs,
                                                const float* __restrict__ asum,
                                                short* __restrict__ state) {
  int blk = blockIdx.x;
  int h = blk & 31, ci = (blk >> 5) & 7, b = blk >> 8;
  int g = h & 7;
  int tid = threadIdx.x, wid = tid >> 6, lane = tid & 63, lg = lane >> 4, lr = lane & 15;
  __shared__ float dsh[256];
  __shared__ short Bt[128 * 40];  // [n][l_local]
  __shared__ short Xt[64 * 40];   // [d][l_local]
  const float* acs_p = acs + ((size_t)((b * HH + h) * NC + ci)) * LCH;
  float last = asum[(b * HH + h) * NC + ci];
  dsh[tid] = __expf(last - acs_p[tid]);
  const short* Bbase = Bbf + ((size_t)(b * S_ + ci * LCH) * GG + g) * NST;
  const short* Xbase = xdt + (size_t)(b * S_ + ci * LCH) * DM + h * DH;
  const int lrow = tid >> 3, nseg = (tid & 7) * 16, dseg = (tid & 7) * 8;
  f32x4 acc[2][4] = {};
  for (int l0 = 0; l0 < LCH; l0 += 32) {
    uint4 b0 = *(const uint4*)(Bbase + (size_t)(l0 + lrow) * (GG * NST) + nseg);
    uint4 b1 = *(const uint4*)(Bbase + (size_t)(l0 + lrow) * (GG * NST) + nseg + 8);
    uint4 xv = *(const uint4*)(Xbase + (size_t)(l0 + lrow) * DM + dseg);
    __syncthreads();
    float dly = dsh[l0 + lrow];
    const short* bp0 = (const short*)&b0;
    for (int e = 0; e < 8; ++e) Bt[(nseg + e) * 40 + lrow] = f2bf(bf2f(bp0[e]) * dly);
    const short* bp1 = (const short*)&b1;
    for (int e = 0; e < 8; ++e) Bt[(nseg + 8 + e) * 40 + lrow] = f2bf(bf2f(bp1[e]) * dly);
    const short* xp = (const short*)&xv;
    for (int e = 0; e < 8; ++e) Xt[(dseg + e) * 40 + lrow] = xp[e];
    __syncthreads();
    bf16x8 afr[2], bfr[4];
    for (int mi = 0; mi < 2; ++mi)
      afr[mi] = *(const bf16x8*)(Bt + (wid * 32 + mi * 16 + lr) * 40 + lg * 8);
    for (int ni = 0; ni < 4; ++ni)
      bfr[ni] = *(const bf16x8*)(Xt + (ni * 16 + lr) * 40 + lg * 8);
    for (int mi = 0; mi < 2; ++mi)
      for (int ni = 0; ni < 4; ++ni)
        acc[mi][ni] = __builtin_amdgcn_mfma_f32_16x16x32_bf16(afr[mi], bfr[ni], acc[mi][ni], 0, 0, 0);
  }
  short* sp = state + (size_t)blk * DH * NST;
  for (int mi = 0; mi < 2; ++mi)
    for (int ni = 0; ni < 4; ++ni)
      for (int r = 0; r < 4; ++r) {
        int n = wid * 32 + mi * 16 + lg * 4 + r;
        int d = ni * 16 + lr;
        sp[d * NST + n] = f2bf(acc[mi][ni][r]);
      }
}

// ---------------- Y kernel: Y_off + triangular Y_diag + D*x, writes bf16 ----------------
__global__ __launch_bounds__(256) void k_y(const short* __restrict__ Cbf,
                                           const short* __restrict__ Bbf,
                                           const short* __restrict__ xdt,
                                           const float* __restrict__ xraw,
                                           const float* __restrict__ acs,
                                           const float* __restrict__ csum,
                                           const short* __restrict__ state,
                                           const float* __restrict__ Dv,
                                           short* __restrict__ Ybuf) {
  int blk = blockIdx.x;
  int h = blk & 31, ci = (blk >> 5) & 7, b = blk >> 8;
  int g = h & 7;
  int tid = threadIdx.x, wid = tid >> 6, lane = tid & 63, lg = lane >> 4, lr = lane & 15;
  __shared__ float ash[256];
  __shared__ short Xt[64 * 264];    // [d][l], stride 264
  __shared__ short Mld[4][64 * 40]; // per-wave M tile
  const float* acs_p = acs + ((size_t)((b * HH + h) * NC + ci)) * LCH;
  ash[tid] = acs_p[tid];
  float cs = csum[(b * HH + h) * NC + ci];
  const short* Xbase = xdt + (size_t)(b * S_ + ci * LCH) * DM + h * DH;
  {
    const short* xr = Xbase + (size_t)tid * DM;
    for (int d0 = 0; d0 < DH; d0 += 8) {
      uint4 v = *(const uint4*)(xr + d0);
      const short* vp = (const short*)&v;
      for (int e = 0; e < 8; ++e) Xt[(d0 + e) * 264 + tid] = vp[e];
    }
  }
  __syncthreads();
  f32x4 acc[4][4] = {};
  const short* Crow0 = Cbf + ((size_t)(b * S_ + ci * LCH) * GG + g) * NST;
  // ---- Y_off: C @ state_{ci-1}^T, scaled by exp(A_cs[i]) * col_sum ----
  if (ci > 0) {
    const short* sp = state + (size_t)((b * NC + ci - 1) * HH + h) * DH * NST;
    for (int n0 = 0; n0 < NST; n0 += 32) {
      bf16x8 afr[4], bfr[4];
      for (int mi = 0; mi < 4; ++mi)
        afr[mi] = *(const bf16x8*)(Crow0 + (size_t)(wid * 64 + mi * 16 + lr) * (GG * NST) + n0 + lg * 8);
      for (int ni = 0; ni < 4; ++ni)
        bfr[ni] = *(const bf16x8*)(sp + (ni * 16 + lr) * NST + n0 + lg * 8);
      for (int mi = 0; mi < 4; ++mi)
        for (int ni = 0; ni < 4; ++ni)
          acc[mi][ni] = __builtin_amdgcn_mfma_f32_16x16x32_bf16(afr[mi], bfr[ni], acc[mi][ni], 0, 0, 0);
    }
    for (int mi = 0; mi < 4; ++mi)
      for (int r = 0; r < 4; ++r) {
        int i = wid * 64 + mi * 16 + lg * 4 + r;
        float f = __expf(ash[i]) * cs;
        for (int ni = 0; ni < 4; ++ni) acc[mi][ni][r] *= f;
      }
  }
  // ---- Y_diag: per-wave triangular j-tile loop (no cross-wave sync) ----
  short* Ml = &Mld[wid][0];
  int jtmax = (wid * 64 + 63) >> 5;
  for (int jt = 0; jt <= jtmax; ++jt) {
    f32x4 gacc[4][2] = {};
    for (int n0 = 0; n0 < NST; n0 += 32) {
      bf16x8 afr[4], bfr[2];
      for (int mi = 0; mi < 4; ++mi)
        afr[mi] = *(const bf16x8*)(Crow0 + (size_t)(wid * 64 + mi * 16 + lr) * (GG * NST) + n0 + lg * 8);
      for (int nj = 0; nj < 2; ++nj) {
        int j = jt * 32 + nj * 16 + lr;
        bfr[nj] = *(const bf16x8*)(Bbf + ((size_t)(b * S_ + ci * LCH + j) * GG + g) * NST + n0 + lg * 8);
      }
      for (int mi = 0; mi < 4; ++mi)
        for (int nj = 0; nj < 2; ++nj)
          gacc[mi][nj] = __builtin_amdgcn_mfma_f32_16x16x32_bf16(afr[mi], bfr[nj], gacc[mi][nj], 0, 0, 0);
    }
    for (int mi = 0; mi < 4; ++mi)
      for (int nj = 0; nj < 2; ++nj)
        for (int r = 0; r < 4; ++r) {
          int i = wid * 64 + mi * 16 + lg * 4 + r;
          int jc = jt * 32 + nj * 16 + lr;
          float v = 0.f;
          if (jc <= i) v = gacc[mi][nj][r] * __expf(ash[i] - ash[jc]);
          Ml[(mi * 16 + lg * 4 + r) * 40 + nj * 16 + lr] = f2bf(v);
        }
    bf16x8 mfr[4], xfr[4];
    for (int mi = 0; mi < 4; ++mi) mfr[mi] = *(const bf16x8*)(Ml + (mi * 16 + lr) * 40 + lg * 8);
    for (int ni = 0; ni < 4; ++ni) xfr[ni] = *(const bf16x8*)(Xt + (ni * 16 + lr) * 264 + jt * 32 + lg * 8);
    for (int mi = 0; mi < 4; ++mi)
      for (int ni = 0; ni < 4; ++ni)
        acc[mi][ni] = __builtin_amdgcn_mfma_f32_16x16x32_bf16(mfr[mi], xfr[ni], acc[mi][ni], 0, 0, 0);
  }
  // ---- epilogue: + D[h]*x_raw, write bf16 ----
  float Dh = Dv[h];
  const float* xr0 = xraw + (size_t)(b * S_ + ci * LCH) * DM + h * DH;
  short* yb = Ybuf + (size_t)(b * S_ + ci * LCH) * DM + h * DH;
  for (int mi = 0; mi < 4; ++mi)
    for (int r = 0; r < 4; ++r) {
      int i = wid * 64 + mi * 16 + lg * 4 + r;
      for (int ni = 0; ni < 4; ++ni) {
        int d = ni * 16 + lr;
        float v = acc[mi][ni][r] + Dh * xr0[(size_t)i * DM + d];
        yb[(size_t)i * DM + d] = f2bf(v);
      }
    }
}

extern "C" void kernel_launch(void* const* d_in, const int* in_sizes, int n_in,
                              void* d_out, int out_size, void* d_ws, size_t ws_size,
                              hipStream_t stream) {
  const float* hs    = (const float*)d_in[0];
  const float* A_log = (const float*)d_in[1];
  const float* Dv    = (const float*)d_in[2];
  const float* W_B   = (const float*)d_in[3];
  const float* b_B   = (const float*)d_in[4];
  const float* W_C   = (const float*)d_in[5];
  const float* b_C   = (const float*)d_in[6];
  const float* W_x   = (const float*)d_in[7];
  const float* b_x   = (const float*)d_in[8];
  const float* W_dt  = (const float*)d_in[9];
  const float* b_dt  = (const float*)d_in[10];
  const float* W_out = (const float*)d_in[11];
  const float* b_out = (const float*)d_in[12];

  char* w = (char*)d_ws;
  size_t off = 0;
  auto alloc = [&](size_t bytes) -> char* {
    char* p = w + off;
    off += (bytes + 255) & ~(size_t)255;
    return p;
  };
  short* hs_bf = (short*)alloc((size_t)MR * DM * 2);
  short* WxT   = (short*)alloc((size_t)DM * DM * 2);
  short* WBT   = (short*)alloc((size_t)1024 * DM * 2);
  short* WCT   = (short*)alloc((size_t)1024 * DM * 2);
  short* WdtT  = (short*)alloc((size_t)32 * DM * 2);
  short* WoutT = (short*)alloc((size_t)DM * DM * 2);
  float* xraw  = (float*)alloc((size_t)MR * DM * 4);
  short* Bbf   = (short*)alloc((size_t)MR * 1024 * 2);
  short* Cbf   = (short*)alloc((size_t)MR * 1024 * 2);
  float* dtraw = (float*)alloc((size_t)MR * HH * 4);
  float* dtsp  = (float*)alloc((size_t)MR * HH * 4);
  float* adt   = (float*)alloc((size_t)MR * HH * 4);
  float* acs   = (float*)alloc((size_t)BB * HH * NC * LCH * 4);
  float* asum  = (float*)alloc((size_t)BB * HH * NC * 4);
  float* csum  = (float*)alloc((size_t)BB * HH * NC * 4);
  short* state = (short*)alloc((size_t)BB * NC * HH * DH * NST * 2);
  short* xdtbf = (short*)alloc((size_t)MR * DM * 2);
  short* Ybuf  = (short*)alloc((size_t)MR * DM * 2);
  (void)ws_size; (void)in_sizes; (void)n_in; (void)out_size;

  // casts / transposes
  k_cast<<<(MR * DM / 8 + 255) / 256, 256, 0, stream>>>(hs, hs_bf, MR * DM / 8);
  k_cast_T<<<dim3(DM / 32, DM / 32), 256, 0, stream>>>(W_x, WxT, DM, DM);
  k_cast_T<<<dim3(1024 / 32, DM / 32), 256, 0, stream>>>(W_B, WBT, DM, 1024);
  k_cast_T<<<dim3(1024 / 32, DM / 32), 256, 0, stream>>>(W_C, WCT, DM, 1024);
  k_cast_T<<<dim3(1, DM / 32), 256, 0, stream>>>(W_dt, WdtT, DM, 32);
  k_cast_T<<<dim3(DM / 32, DM / 32), 256, 0, stream>>>(W_out, WoutT, DM, DM);

  // projections (128-tile MFMA GEMMs; dt stays on the 64-tile path, N=32)
  k_gemm<0><<<dim3(1, MR / 64), 256, 0, stream>>>(hs_bf, WdtT, b_dt, dtraw, MR, 32, KD);
  k_gemm128<0><<<dim3(DM / 128, MR / 128), 256, 0, stream>>>(hs_bf, WxT, b_x, xraw, MR, DM, KD);
  k_gemm128<1><<<dim3(1024 / 128, MR / 128), 256, 0, stream>>>(hs_bf, WBT, b_B, Bbf, MR, 1024, KD);
  k_gemm128<1><<<dim3(1024 / 128, MR / 128), 256, 0, stream>>>(hs_bf, WCT, b_C, Cbf, MR, 1024, KD);

  // elementwise + scans
  k_dt<<<(MR * HH + 255) / 256, 256, 0, stream>>>(dtraw, A_log, dtsp, adt, MR * HH);
  k_xdt<<<(MR * DM / 4 + 255) / 256, 256, 0, stream>>>(xraw, dtsp, xdtbf, MR * DM / 4);
  k_scan<<<BB * HH * NC, 256, 0, stream>>>(adt, acs, asum);
  k_colsum<<<1, 64, 0, stream>>>(asum, csum);

  // SSD core
  k_states<<<BB * NC * HH, 256, 0, stream>>>(Bbf, xdtbf, acs, asum, state);
  k_y<<<BB * NC * HH, 256, 0, stream>>>(Cbf, Bbf, xdtbf, xraw, acs, csum, state, Dv, Ybuf);

  // output projection
  k_gemm128<0><<<dim3(DM / 128, MR / 128), 256, 0, stream>>>(Ybuf, WoutT, b_out, (float*)d_out, MR, DM, KD);
}